// Round 12
// baseline (441.926 us; speedup 1.0000x reference)
//
#include <hip/hip_runtime.h>
#include <hip/hip_bf16.h>
#include <hip/hip_fp16.h>

#define TPB 256
#define TPBO 512

typedef __attribute__((ext_vector_type(8))) short s8v;     // 8 bf16 (4 VGPR) MFMA A/B frag
typedef __attribute__((ext_vector_type(4))) float f32x4;   // MFMA C/D frag
typedef unsigned short u16;

__device__ __forceinline__ u16 f2bf(float f){
  union { __hip_bfloat16 h; u16 u; } cv;
  cv.h = __float2bfloat16(f);            // HW cvt (pairs fuse to v_cvt_pk_bf16_f32)
  return cv.u;
}

__device__ __forceinline__ unsigned pack_bf2(float lo, float hi){
  return (unsigned)f2bf(lo) | ((unsigned)f2bf(hi) << 16);
}

__device__ __forceinline__ float bflo(unsigned u){ return __uint_as_float(u << 16); }
__device__ __forceinline__ float bfhi(unsigned u){ return __uint_as_float(u & 0xffff0000u); }

__device__ __forceinline__ int wave_incl_scan(int v, int lane){
  #pragma unroll
  for (int off=1; off<64; off<<=1){
    int u = __shfl_up(v, off, 64);
    if (lane >= off) v += u;
  }
  return v;
}

// ---------------- CSR build ----------------
__global__ __launch_bounds__(TPB) void count_k(const int* __restrict__ dstE, int* __restrict__ cnt, int E){
  int e = blockIdx.x*TPB + threadIdx.x;
  if (e < E) atomicAdd(&cnt[dstE[e]], 1);
}

__global__ __launch_bounds__(TPB) void scan1_k(const int* __restrict__ cnt, int* __restrict__ rowptr,
                                               int* __restrict__ bsum, float* __restrict__ disp, int nN){
  int t = threadIdx.x;
  int i = blockIdx.x*TPB + t;
  int lane = t & 63, wid = t >> 6;
  int v = (i < nN) ? cnt[i] : 0;
  if (i < nN) disp[i] = rsqrtf((float)v + 1.0f);   // deg incl self-loop
  int inc = wave_incl_scan(v, lane);
  __shared__ int wsum[4];
  if (lane == 63) wsum[wid] = inc;
  __syncthreads();
  int off = 0;
  #pragma unroll
  for (int w=0; w<4; ++w) if (w < wid) off += wsum[w];
  if (i < nN) rowptr[i] = inc - v + off;
  if (t == 0) bsum[blockIdx.x] = wsum[0]+wsum[1]+wsum[2]+wsum[3];
}

__global__ __launch_bounds__(TPB) void scan2_k(int* __restrict__ bsum, int nbk){
  int t = threadIdx.x;
  int lane = t & 63, wid = t >> 6;
  int v = (t < nbk) ? bsum[t] : 0;
  int inc = wave_incl_scan(v, lane);
  __shared__ int wsum[4];
  if (lane == 63) wsum[wid] = inc;
  __syncthreads();
  int off = 0;
  #pragma unroll
  for (int w=0; w<4; ++w) if (w < wid) off += wsum[w];
  __syncthreads();
  if (t < nbk) bsum[t] = inc - v + off;
}

__global__ __launch_bounds__(TPB) void scan3_k(int* __restrict__ rowptr, const int* __restrict__ bsum, int nN, int E){
  int i = blockIdx.x*TPB + threadIdx.x;
  if (i < nN) rowptr[i] += bsum[blockIdx.x];
  if (i == 0) rowptr[nN] = E;
}

__global__ __launch_bounds__(TPB) void fill_k(const int* __restrict__ srcE, const int* __restrict__ dstE,
                                              const int* __restrict__ rowptr, int* __restrict__ cursor,
                                              int* __restrict__ csr, int E){
  int e = blockIdx.x*TPB + threadIdx.x;
  if (e >= E) return;
  int d = dstE[e];
  int pos = atomicAdd(&cursor[d], 1);
  csr[rowptr[d] + pos] = srcE[e];
}

// ---------------- weight pre-arrangement into MFMA B-fragment order ----------------
__global__ __launch_bounds__(TPB) void prep_wpre_k(const float* __restrict__ sw, const float* __restrict__ bw,
                                                   u16* __restrict__ wpre, int IN, int KSTEPS, int NTILES, int OUTW){
  int idx = blockIdx.x*TPB + threadIdx.x;
  if (idx >= NTILES*KSTEPS*512) return;
  int b = idx & 7, lane = (idx >> 3) & 63, rest = idx >> 9;
  int kstep = rest % KSTEPS, nt = rest / KSTEPS;
  int chunk = kstep / 5, g = kstep % 5;
  int d = chunk*32 + ((lane >> 4)*8 + b);
  int n = nt*16 + (lane & 15);
  float v = 0.f;
  if (n < OUTW) v = (g < 4) ? sw[(size_t)n*IN*4 + d*4 + g] : bw[(size_t)n*IN + d];
  wpre[idx] = f2bf(v);
}

// ---------------- A-fragment build: 8 dims -> 5 bf16x8 frags (4 basis + silu) ----------------
// exp2-domain: exp(-z^2) = exp2(-(z*sqrt(log2 e))^2); grid constants pre-scaled.
__device__ __forceinline__ void build_frags(const float* __restrict__ h8, float mean, float rstd,
                                            const float* __restrict__ lngv, const float* __restrict__ lnbv,
                                            s8v* __restrict__ a){
  float bas[5][8];
  #pragma unroll
  for (int u=0; u<8; ++u){
    float v = h8[u];
    float xn = (v - mean)*rstd*lngv[u] + lnbv[u];
    float y = 0.900841806f*xn;                      // 0.75 * sqrt(log2 e) * xn
    float d0 = y + 1.80168361f;                     // grid' = {-1.8017,-0.6006,0.6006,1.8017}
    float d1 = y + 0.600561204f;
    float d2 = y - 0.600561204f;
    float d3 = y - 1.80168361f;
    bas[0][u] = __builtin_amdgcn_exp2f(-d0*d0);
    bas[1][u] = __builtin_amdgcn_exp2f(-d1*d1);
    bas[2][u] = __builtin_amdgcn_exp2f(-d2*d2);
    bas[3][u] = __builtin_amdgcn_exp2f(-d3*d3);
    float e = __builtin_amdgcn_exp2f(-1.44269504f*v);
    bas[4][u] = v * __builtin_amdgcn_rcpf(1.f + e); // silu
  }
  #pragma unroll
  for (int g=0; g<5; ++g){
    #pragma unroll
    for (int j=0; j<4; ++j)
      ((unsigned*)&a[g])[j] = pack_bf2(bas[g][2*j], bas[g][2*j+1]);
  }
}

// ---------------- fused FKAN layer: j-split, no LDS, no barriers ----------------
template<bool BF16IN>
__global__ __launch_bounds__(TPB) void fkan_layer_k(
    const float* __restrict__ in32, const u16* __restrict__ in16,
    const float* __restrict__ scsh,
    const float* __restrict__ lng, const float* __restrict__ lnb,
    const u16* __restrict__ wpre, const float* __restrict__ bias,
    const float* __restrict__ disp, u16* __restrict__ hs, int nN)
{
  const int t = threadIdx.x;
  const int wv = blockIdx.x*(TPB/64) + (t >> 6);
  const int ngrp = (nN + 15) >> 4;
  const int ng = wv >> 1, jh = wv & 1;
  if (ng >= ngrp) return;
  const int l = t & 63, clo = l & 15, kq = l >> 4;
  const int node = ng*16 + clo;
  const int nc = node < nN ? node : nN-1;

  float h[4][8];
  #pragma unroll
  for (int c=0; c<4; ++c){
    if (BF16IN){
      uint4 raw = *(const uint4*)(in16 + (size_t)nc*128 + c*32 + kq*8);
      h[c][0]=bflo(raw.x); h[c][1]=bfhi(raw.x);
      h[c][2]=bflo(raw.y); h[c][3]=bfhi(raw.y);
      h[c][4]=bflo(raw.z); h[c][5]=bfhi(raw.z);
      h[c][6]=bflo(raw.w); h[c][7]=bfhi(raw.w);
      #pragma unroll
      for (int u=0; u<8; ++u){
        int d = c*32 + kq*8 + u;
        h[c][u] = fmaf(h[c][u], scsh[d], scsh[128 + d]);
      }
    } else {
      const float* hrow = in32 + (size_t)nc*128;
      *(float4*)&h[c][0] = *(const float4*)(hrow + c*32 + kq*8);
      *(float4*)&h[c][4] = *(const float4*)(hrow + c*32 + kq*8 + 4);
    }
  }
  // fused LayerNorm stats
  float s = 0.f, sq = 0.f;
  #pragma unroll
  for (int c=0; c<4; ++c)
    #pragma unroll
    for (int u=0; u<8; ++u){ float v = h[c][u]; s += v; sq += v*v; }
  s  += __shfl_xor(s, 16, 64);  s  += __shfl_xor(s, 32, 64);
  sq += __shfl_xor(sq, 16, 64); sq += __shfl_xor(sq, 32, 64);
  float mean = s * (1.f/128.f);
  float var  = fmaxf(sq * (1.f/128.f) - mean*mean, 0.f);
  float rstd = rsqrtf(var + 1e-5f);

  f32x4 acc[4];
  #pragma unroll
  for (int j=0; j<4; ++j) acc[j] = (f32x4)0.f;

  for (int c=0; c<4; ++c){
    float lngv[8], lnbv[8];
    *(float4*)&lngv[0] = *(const float4*)(lng + c*32 + kq*8);
    *(float4*)&lngv[4] = *(const float4*)(lng + c*32 + kq*8 + 4);
    *(float4*)&lnbv[0] = *(const float4*)(lnb + c*32 + kq*8);
    *(float4*)&lnbv[4] = *(const float4*)(lnb + c*32 + kq*8 + 4);
    s8v a[5];
    build_frags(h[c], mean, rstd, lngv, lnbv, a);
    #pragma unroll
    for (int ks=0; ks<5; ++ks){
      const int kglob = c*5 + ks;
      #pragma unroll
      for (int j=0; j<4; ++j){
        s8v b = *(const s8v*)(wpre + ((size_t)((jh*4 + j)*20 + kglob)*64 + l)*8);
        acc[j] = __builtin_amdgcn_mfma_f32_16x16x32_bf16(a[ks], b, acc[j], 0, 0, 0);
      }
    }
  }
  // epilogue: C/D col = clo, row = kq*4+rr ; hs = (acc+bias)*disp[node], bf16
  float bv[4];
  #pragma unroll
  for (int j=0; j<4; ++j) bv[j] = bias[(jh*4 + j)*16 + clo];
  #pragma unroll
  for (int rr=0; rr<4; ++rr){
    int nw = ng*16 + kq*4 + rr;
    if (nw < nN){
      float dsc = disp[nw];
      #pragma unroll
      for (int j=0; j<4; ++j)
        hs[(size_t)nw*128 + (jh*4 + j)*16 + clo] = f2bf((acc[j][rr] + bv[j]) * dsc);
    }
  }
}

// ---------------- final FKAN: 8 waves x 2 chunks, 32 nodes/block; fused LN-512 + BN fold ----
// f16 partial accumulators in LDS (26.6 KB total -> 6 blocks/CU)
__global__ __launch_bounds__(TPBO, 4) void fkan_out_k(
    const float* __restrict__ x, const u16* __restrict__ hl16,
    const float* __restrict__ scshAll,
    const float* __restrict__ lng, const float* __restrict__ lnb,
    const u16* __restrict__ wpre, const float* __restrict__ bias,
    float* __restrict__ out, int nN)
{
  __shared__ float sstat[8][16][4];     // [wave][clo][{s0,q0,s1,q1}]
  __shared__ __half sred[8][24][64];
  const int t = threadIdx.x;
  const int w = t >> 6, l = t & 63, clo = l & 15, kq = l >> 4;
  const int nb0 = blockIdx.x * 32;
  int nc0 = nb0 + clo;      nc0 = nc0 < nN ? nc0 : nN-1;
  int nc1 = nb0 + 16 + clo; nc1 = nc1 < nN ? nc1 : nN-1;

  // ---- load this wave's 2 chunks for both node groups (BN folded for hl part)
  float h0[2][8], h1[2][8];
  #pragma unroll
  for (int cc=0; cc<2; ++cc){
    const int c = w*2 + cc;
    const int d0 = c*32 + kq*8;
    if (d0 < 128){
      const float* s0 = x + (size_t)nc0*128 + d0;
      const float* s1 = x + (size_t)nc1*128 + d0;
      *(float4*)&h0[cc][0] = *(const float4*)(s0);  *(float4*)&h0[cc][4] = *(const float4*)(s0+4);
      *(float4*)&h1[cc][0] = *(const float4*)(s1);  *(float4*)&h1[cc][4] = *(const float4*)(s1+4);
    } else {
      int dd = d0 - 128, li = dd >> 7, cc2 = dd & 127;
      uint4 r0 = *(const uint4*)(hl16 + ((size_t)li*nN + nc0)*128 + cc2);
      uint4 r1 = *(const uint4*)(hl16 + ((size_t)li*nN + nc1)*128 + cc2);
      h0[cc][0]=bflo(r0.x); h0[cc][1]=bfhi(r0.x); h0[cc][2]=bflo(r0.y); h0[cc][3]=bfhi(r0.y);
      h0[cc][4]=bflo(r0.z); h0[cc][5]=bfhi(r0.z); h0[cc][6]=bflo(r0.w); h0[cc][7]=bfhi(r0.w);
      h1[cc][0]=bflo(r1.x); h1[cc][1]=bfhi(r1.x); h1[cc][2]=bflo(r1.y); h1[cc][3]=bfhi(r1.y);
      h1[cc][4]=bflo(r1.z); h1[cc][5]=bfhi(r1.z); h1[cc][6]=bflo(r1.w); h1[cc][7]=bfhi(r1.w);
      #pragma unroll
      for (int u=0; u<8; ++u){
        float sc = scshAll[li*256 + cc2 + u], sh = scshAll[li*256 + 128 + cc2 + u];
        h0[cc][u] = fmaf(h0[cc][u], sc, sh);
        h1[cc][u] = fmaf(h1[cc][u], sc, sh);
      }
    }
  }
  // ---- fused LN-512 stats: lane partial -> kq reduce -> cross-wave LDS reduce
  float s0=0.f, q0=0.f, s1=0.f, q1=0.f;
  #pragma unroll
  for (int cc=0; cc<2; ++cc)
    #pragma unroll
    for (int u=0; u<8; ++u){
      float a0v = h0[cc][u], a1v = h1[cc][u];
      s0 += a0v; q0 += a0v*a0v;
      s1 += a1v; q1 += a1v*a1v;
    }
  s0 += __shfl_xor(s0, 16, 64); s0 += __shfl_xor(s0, 32, 64);
  q0 += __shfl_xor(q0, 16, 64); q0 += __shfl_xor(q0, 32, 64);
  s1 += __shfl_xor(s1, 16, 64); s1 += __shfl_xor(s1, 32, 64);
  q1 += __shfl_xor(q1, 16, 64); q1 += __shfl_xor(q1, 32, 64);
  if (l < 16){
    sstat[w][clo][0] = s0; sstat[w][clo][1] = q0;
    sstat[w][clo][2] = s1; sstat[w][clo][3] = q1;
  }
  __syncthreads();
  float S0=0.f, Q0=0.f, S1=0.f, Q1=0.f;
  #pragma unroll
  for (int ww=0; ww<8; ++ww){
    S0 += sstat[ww][clo][0]; Q0 += sstat[ww][clo][1];
    S1 += sstat[ww][clo][2]; Q1 += sstat[ww][clo][3];
  }
  const float mean0 = S0 * (1.f/512.f);
  const float rstd0 = rsqrtf(fmaxf(Q0*(1.f/512.f) - mean0*mean0, 0.f) + 1e-5f);
  const float mean1 = S1 * (1.f/512.f);
  const float rstd1 = rsqrtf(fmaxf(Q1*(1.f/512.f) - mean1*mean1, 0.f) + 1e-5f);

  f32x4 acc[2][3];
  #pragma unroll
  for (int m=0; m<2; ++m)
    #pragma unroll
    for (int j=0; j<3; ++j) acc[m][j] = (f32x4)0.f;

  #pragma unroll
  for (int cc=0; cc<2; ++cc){
    const int c = w*2 + cc;
    const int d0 = c*32 + kq*8;
    float lngv[8], lnbv[8];
    *(float4*)&lngv[0] = *(const float4*)(lng + d0);
    *(float4*)&lngv[4] = *(const float4*)(lng + d0 + 4);
    *(float4*)&lnbv[0] = *(const float4*)(lnb + d0);
    *(float4*)&lnbv[4] = *(const float4*)(lnb + d0 + 4);
    s8v a0[5], a1[5];
    build_frags(h0[cc], mean0, rstd0, lngv, lnbv, a0);
    build_frags(h1[cc], mean1, rstd1, lngv, lnbv, a1);
    #pragma unroll
    for (int ks=0; ks<5; ++ks){
      const int kglob = c*5 + ks;
      #pragma unroll
      for (int j=0; j<3; ++j){
        s8v b = *(const s8v*)(wpre + ((size_t)(j*80 + kglob)*64 + l)*8);
        acc[0][j] = __builtin_amdgcn_mfma_f32_16x16x32_bf16(a0[ks], b, acc[0][j], 0, 0, 0);
        acc[1][j] = __builtin_amdgcn_mfma_f32_16x16x32_bf16(a1[ks], b, acc[1][j], 0, 0, 0);
      }
    }
  }
  #pragma unroll
  for (int m=0; m<2; ++m)
    #pragma unroll
    for (int j=0; j<3; ++j)
      #pragma unroll
      for (int rr=0; rr<4; ++rr)
        sred[w][m*12 + j*4 + rr][l] = __float2half(acc[m][j][rr]);
  __syncthreads();
  // parallel reduce + store: 24 slots x 64 lanes = 1536 items over 512 threads
  #pragma unroll
  for (int k=0; k<3; ++k){
    int q = t + k*TPBO;
    int slot = q >> 6, l2 = q & 63;
    float val = 0.f;
    #pragma unroll
    for (int ww=0; ww<8; ++ww) val += __half2float(sred[ww][slot][l2]);
    int m = slot >= 12 ? 1 : 0;
    int jrr = slot - m*12;
    int j = jrr >> 2, rr = jrr & 3;
    int nodeq = nb0 + m*16 + (l2 >> 4)*4 + rr;
    int col = j*16 + (l2 & 15);
    if (nodeq < nN && col < 40)
      out[(size_t)nodeq*40 + col] = val + bias[col];
  }
}

// ---------------- GCN aggregation + fused BN stats ----------------
// node per quarter-wave, grid-stride; per-thread BN accumulators (lane li owns channels li*8..+7)
__device__ __forceinline__ void acc_bf8(uint4 u, float* __restrict__ a){
  a[0] += bflo(u.x); a[1] += bfhi(u.x);
  a[2] += bflo(u.y); a[3] += bfhi(u.y);
  a[4] += bflo(u.z); a[5] += bfhi(u.z);
  a[6] += bflo(u.w); a[7] += bfhi(u.w);
}

__global__ __launch_bounds__(TPB) void gcn_k(const u16* __restrict__ hs, const int* __restrict__ rowptr,
                                             const int* __restrict__ csr, const float* __restrict__ disp,
                                             u16* __restrict__ hl, float* __restrict__ stats, int nN){
  __shared__ float lstat[256];
  for (int i=threadIdx.x; i<256; i+=TPB) lstat[i] = 0.f;
  __syncthreads();
  const int li = threadIdx.x & 15;
  const int tq0 = (blockIdx.x*TPB + threadIdx.x) >> 4;       // this thread's quarter slot
  const int qstride = (gridDim.x*TPB) >> 4;
  const uint4* H4 = (const uint4*)hs;                        // 16 uint4 per row (128 bf16)
  float bs[8], bq[8];
  #pragma unroll
  for (int j=0; j<8; ++j){ bs[j]=0.f; bq[j]=0.f; }

  for (int n = tq0; n < nN; n += qstride){
    int e0 = rowptr[n], e1 = rowptr[n+1];
    float a[8];
    #pragma unroll
    for (int j=0; j<8; ++j) a[j] = 0.f;
    for (int base = e0; base < e1; base += 4){
      int r[4];
      #pragma unroll
      for (int k=0; k<4; ++k){
        int idx = base + k;
        int idc = idx < e1 ? idx : e1-1;      // safe address (loop implies e1>e0)
        int rv  = csr[idc];                   // uniform across the 16 lanes (L1 broadcast)
        r[k] = idx < e1 ? rv : nN;            // row nN = zero sentinel
      }
      #pragma unroll
      for (int k=0; k<4; ++k){
        uint4 u = H4[(size_t)r[k]*16 + li];
        acc_bf8(u, a);
      }
    }
    uint4 u = H4[(size_t)n*16 + li];          // self-loop (hs already has dis[n] factor)
    acc_bf8(u, a);
    float dn = disp[n];
    #pragma unroll
    for (int j=0; j<8; ++j){
      float v = a[j]*dn;
      a[j] = v;
      bs[j] += v;
      bq[j] += v*v;
    }
    uint4 o;
    o.x = pack_bf2(a[0], a[1]);
    o.y = pack_bf2(a[2], a[3]);
    o.z = pack_bf2(a[4], a[5]);
    o.w = pack_bf2(a[6], a[7]);
    *(uint4*)(hl + (size_t)n*128 + li*8) = o; // 256B contiguous per quarter
  }
  // block-level BN reduce (LDS atomics), then one global atomic per channel slot
  #pragma unroll
  for (int j=0; j<8; ++j){
    atomicAdd(&lstat[li*8 + j], bs[j]);
    atomicAdd(&lstat[128 + li*8 + j], bq[j]);
  }
  __syncthreads();
  atomicAdd(&stats[threadIdx.x], lstat[threadIdx.x]);
}

// bn_fin reads stats, emits scale/shift, and re-zeros stats for the next layer
__global__ void bn_fin_k(float* __restrict__ stats, const float* __restrict__ g, const float* __restrict__ b,
                         float* __restrict__ scsh, int nN){
  int c = threadIdx.x;
  float inv = 1.f/(float)nN;
  float m = stats[c]*inv;
  float var = fmaxf(stats[128+c]*inv - m*m, 0.f);
  float sc = g[c]*rsqrtf(var + 1e-5f);
  scsh[c] = sc;
  scsh[128+c] = b[c] - m*sc;
  stats[c] = 0.f;
  stats[128+c] = 0.f;
}

extern "C" void kernel_launch(void* const* d_in, const int* in_sizes, int n_in,
                              void* d_out, int out_size, void* d_ws, size_t ws_size,
                              hipStream_t stream)
{
  const float* x        = (const float*)d_in[0];
  const int*   ei       = (const int*)d_in[1];
  const float* ln_g     = (const float*)d_in[2];
  const float* ln_b     = (const float*)d_in[3];
  const float* sw       = (const float*)d_in[4];
  const float* bw       = (const float*)d_in[5];
  const float* bb       = (const float*)d_in[6];
  // d_in[7] gcn_bias: canceled exactly by BatchNorm mean subtraction. Skipped.
  const float* bn_g     = (const float*)d_in[8];
  const float* bn_b     = (const float*)d_in[9];
  const float* ln_g_out = (const float*)d_in[10];
  const float* ln_b_out = (const float*)d_in[11];
  const float* sw_out   = (const float*)d_in[12];
  const float* bw_out   = (const float*)d_in[13];
  const float* bb_out   = (const float*)d_in[14];
  float* out = (float*)d_out;

  const int nN = in_sizes[0] / 128;    // 50000
  const int E  = in_sizes[1] / 2;      // 800000

  char* ws = (char*)d_ws;
  size_t off = 0;
  auto alloc = [&](size_t bytes)->char*{
    char* p = ws + off; off = (off + bytes + 255) & ~size_t(255); return p;
  };
  u16*   hl16  = (u16*)alloc((size_t)3*nN*128*2);   // per-layer raw GCN aggregate, bf16
  u16*   hs    = (u16*)alloc((size_t)(nN+1)*128*2); // pre-scaled bf16 FKAN output + zero sentinel row
  float* disp  = (float*)alloc((size_t)nN*4);
  float* stats = (float*)alloc(256*4);
  float* scshL = (float*)alloc(3*256*4);            // per-layer BN scale/shift
  u16*   wpreL = (u16*)alloc((size_t)3*8*20*512*2); // per-layer staged weights
  u16*   wpreO = (u16*)alloc((size_t)3*80*512*2);
  int* cnt     = (int*)alloc((size_t)nN*4);
  int* cursor  = (int*)alloc((size_t)nN*4);
  int* rowptr  = (int*)alloc((size_t)(nN+1)*4);
  int* bsum    = (int*)alloc(256*4);
  int* csr     = (int*)alloc((size_t)E*4);
  (void)ws_size; (void)n_in; (void)out_size;

  const int* srcE = ei;
  const int* dstE = ei + E;

  hipMemsetAsync(cnt, 0, (size_t)nN*4, stream);
  hipMemsetAsync(cursor, 0, (size_t)nN*4, stream);
  hipMemsetAsync(stats, 0, 256*4, stream);
  hipMemsetAsync(hs + (size_t)nN*128, 0, 256, stream);   // zero sentinel row

  // stage all weights up-front (overlaps with CSR build)
  for (int i=0; i<3; ++i)
    prep_wpre_k<<<(8*20*512 + TPB-1)/TPB, TPB, 0, stream>>>(
        sw + (size_t)i*128*512, bw + (size_t)i*128*128, wpreL + (size_t)i*8*20*512, 128, 20, 8, 128);
  prep_wpre_k<<<(3*80*512 + TPB-1)/TPB, TPB, 0, stream>>>(
      sw_out, bw_out, wpreO, 512, 80, 3, 40);

  const int nbE = (E + TPB-1)/TPB;
  const int nbN = (nN + TPB-1)/TPB;
  count_k<<<nbE, TPB, 0, stream>>>(dstE, cnt, E);
  scan1_k<<<nbN, TPB, 0, stream>>>(cnt, rowptr, bsum, disp, nN);
  scan2_k<<<1, TPB, 0, stream>>>(bsum, nbN);
  scan3_k<<<nbN, TPB, 0, stream>>>(rowptr, bsum, nN, E);
  fill_k<<<nbE, TPB, 0, stream>>>(srcE, dstE, rowptr, cursor, csr, E);

  const int nbG = 1024;                                 // gcn: grid-stride, node per quarter-wave
  const int nbL = (((nN + 15)/16)*2 + 3)/4;             // fkan layer: 2 j-half waves per 16 nodes
  const int nbO = (nN + 31)/32;                         // fkan out: 32 nodes/block, 8-wave K-split

  for (int i=0; i<3; ++i){
    if (i == 0){
      fkan_layer_k<false><<<nbL, TPB, 0, stream>>>(
          x, (const u16*)nullptr, (const float*)nullptr,
          ln_g, ln_b, wpreL, bb, disp, hs, nN);
    } else {
      fkan_layer_k<true><<<nbL, TPB, 0, stream>>>(
          (const float*)nullptr, hl16 + (size_t)(i-1)*nN*128, scshL + (size_t)(i-1)*256,
          ln_g + (size_t)i*128, ln_b + (size_t)i*128,
          wpreL + (size_t)i*8*20*512, bb + (size_t)i*128, disp, hs, nN);
    }
    gcn_k<<<nbG, TPB, 0, stream>>>(hs, rowptr, csr, disp, hl16 + (size_t)i*nN*128, stats, nN);
    bn_fin_k<<<1, 128, 0, stream>>>(stats, bn_g + (size_t)i*128, bn_b + (size_t)i*128,
                                    scshL + (size_t)i*256, nN);
  }

  // final FKAN on concat [x | BN(hl)]  (512 -> 40), LN fused in-kernel
  fkan_out_k<<<nbO, TPBO, 0, stream>>>(
      x, hl16, scshL, ln_g_out, ln_b_out, wpreO, bb_out, out, nN);
}

// Round 13
// 402.053 us; speedup vs baseline: 1.0992x; 1.0992x over previous
//
#include <hip/hip_runtime.h>
#include <hip/hip_bf16.h>

#define TPB 256
#define TPBO 512

typedef __attribute__((ext_vector_type(8))) short s8v;     // 8 bf16 (4 VGPR) MFMA A/B frag
typedef __attribute__((ext_vector_type(4))) float f32x4;   // MFMA C/D frag
typedef unsigned short u16;

__device__ __forceinline__ u16 f2bf(float f){
  union { __hip_bfloat16 h; u16 u; } cv;
  cv.h = __float2bfloat16(f);            // HW cvt (pairs fuse to v_cvt_pk_bf16_f32)
  return cv.u;
}

__device__ __forceinline__ unsigned pack_bf2(float lo, float hi){
  return (unsigned)f2bf(lo) | ((unsigned)f2bf(hi) << 16);
}

__device__ __forceinline__ float bflo(unsigned u){ return __uint_as_float(u << 16); }
__device__ __forceinline__ float bfhi(unsigned u){ return __uint_as_float(u & 0xffff0000u); }

__device__ __forceinline__ int wave_incl_scan(int v, int lane){
  #pragma unroll
  for (int off=1; off<64; off<<=1){
    int u = __shfl_up(v, off, 64);
    if (lane >= off) v += u;
  }
  return v;
}

// ---------------- CSR build ----------------
__global__ __launch_bounds__(TPB) void count_k(const int* __restrict__ dstE, int* __restrict__ cnt, int E){
  int e = blockIdx.x*TPB + threadIdx.x;
  if (e < E) atomicAdd(&cnt[dstE[e]], 1);
}

__global__ __launch_bounds__(TPB) void scan1_k(const int* __restrict__ cnt, int* __restrict__ rowptr,
                                               int* __restrict__ bsum, float* __restrict__ disp, int nN){
  int t = threadIdx.x;
  int i = blockIdx.x*TPB + t;
  int lane = t & 63, wid = t >> 6;
  int v = (i < nN) ? cnt[i] : 0;
  if (i < nN) disp[i] = rsqrtf((float)v + 1.0f);   // deg incl self-loop
  int inc = wave_incl_scan(v, lane);
  __shared__ int wsum[4];
  if (lane == 63) wsum[wid] = inc;
  __syncthreads();
  int off = 0;
  #pragma unroll
  for (int w=0; w<4; ++w) if (w < wid) off += wsum[w];
  if (i < nN) rowptr[i] = inc - v + off;
  if (t == 0) bsum[blockIdx.x] = wsum[0]+wsum[1]+wsum[2]+wsum[3];
}

// scan3 with integrated scan2: each block computes its own bsum prefix
__global__ __launch_bounds__(TPB) void scan3_k(int* __restrict__ rowptr, const int* __restrict__ bsum,
                                               int nN, int E, int nbk){
  int t = threadIdx.x;
  int lane = t & 63, wid = t >> 6;
  int v = (t < nbk && t < (int)blockIdx.x) ? bsum[t] : 0;
  #pragma unroll
  for (int off=32; off>0; off>>=1) v += __shfl_xor(v, off, 64);
  __shared__ int wsum[4];
  if (lane == 0) wsum[wid] = v;
  __syncthreads();
  int pre = wsum[0]+wsum[1]+wsum[2]+wsum[3];
  int i = blockIdx.x*TPB + t;
  if (i < nN) rowptr[i] += pre;
  if (i == 0) rowptr[nN] = E;
}

__global__ __launch_bounds__(TPB) void fill_k(const int* __restrict__ srcE, const int* __restrict__ dstE,
                                              const int* __restrict__ rowptr, int* __restrict__ cursor,
                                              int* __restrict__ csr, int E){
  int e = blockIdx.x*TPB + threadIdx.x;
  if (e >= E) return;
  int d = dstE[e];
  int pos = atomicAdd(&cursor[d], 1);
  csr[rowptr[d] + pos] = srcE[e];
}

// ---------------- weight pre-arrangement into MFMA B-fragment order ----------------
__global__ __launch_bounds__(TPB) void prep_wpre_k(const float* __restrict__ sw, const float* __restrict__ bw,
                                                   u16* __restrict__ wpre, int IN, int KSTEPS, int NTILES, int OUTW){
  int idx = blockIdx.x*TPB + threadIdx.x;
  if (idx >= NTILES*KSTEPS*512) return;
  int b = idx & 7, lane = (idx >> 3) & 63, rest = idx >> 9;
  int kstep = rest % KSTEPS, nt = rest / KSTEPS;
  int chunk = kstep / 5, g = kstep % 5;
  int d = chunk*32 + ((lane >> 4)*8 + b);
  int n = nt*16 + (lane & 15);
  float v = 0.f;
  if (n < OUTW) v = (g < 4) ? sw[(size_t)n*IN*4 + d*4 + g] : bw[(size_t)n*IN + d];
  wpre[idx] = f2bf(v);
}

// ---------------- A-fragment build: 8 dims -> 5 bf16x8 frags (4 basis + silu) ----------------
// exp2-domain: exp(-z^2) = exp2(-(z*sqrt(log2 e))^2); grid constants pre-scaled.
__device__ __forceinline__ void build_frags(const float* __restrict__ h8, float mean, float rstd,
                                            const float* __restrict__ lngv, const float* __restrict__ lnbv,
                                            s8v* __restrict__ a){
  float bas[5][8];
  #pragma unroll
  for (int u=0; u<8; ++u){
    float v = h8[u];
    float xn = (v - mean)*rstd*lngv[u] + lnbv[u];
    float y = 0.900841806f*xn;                      // 0.75 * sqrt(log2 e) * xn
    float d0 = y + 1.80168361f;                     // grid' = {-1.8017,-0.6006,0.6006,1.8017}
    float d1 = y + 0.600561204f;
    float d2 = y - 0.600561204f;
    float d3 = y - 1.80168361f;
    bas[0][u] = __builtin_amdgcn_exp2f(-d0*d0);
    bas[1][u] = __builtin_amdgcn_exp2f(-d1*d1);
    bas[2][u] = __builtin_amdgcn_exp2f(-d2*d2);
    bas[3][u] = __builtin_amdgcn_exp2f(-d3*d3);
    float e = __builtin_amdgcn_exp2f(-1.44269504f*v);
    bas[4][u] = v * __builtin_amdgcn_rcpf(1.f + e); // silu
  }
  #pragma unroll
  for (int g=0; g<5; ++g){
    #pragma unroll
    for (int j=0; j<4; ++j)
      ((unsigned*)&a[g])[j] = pack_bf2(bas[g][2*j], bas[g][2*j+1]);
  }
}

// ---------------- fused FKAN layer: j-split; BN scale/shift computed per-block from stats ----
template<bool BF16IN>
__global__ __launch_bounds__(TPB) void fkan_layer_k(
    const float* __restrict__ in32, const u16* __restrict__ in16,
    const float* __restrict__ stats, const float* __restrict__ bng, const float* __restrict__ bnb,
    const float* __restrict__ lng, const float* __restrict__ lnb,
    const u16* __restrict__ wpre, const float* __restrict__ bias,
    const float* __restrict__ disp, u16* __restrict__ hs, int nN)
{
  __shared__ float sscsh[256];
  const int t = threadIdx.x;
  if (BF16IN){
    if (t < 128){
      float inv = 1.f/(float)nN;
      float m = stats[t]*inv;
      float var = fmaxf(stats[128+t]*inv - m*m, 0.f);
      float sc = bng[t]*rsqrtf(var + 1e-5f);
      sscsh[t] = sc;
      sscsh[128+t] = bnb[t] - m*sc;
    }
    __syncthreads();
  }
  const int wv = blockIdx.x*(TPB/64) + (t >> 6);
  const int ngrp = (nN + 15) >> 4;
  const int ng = wv >> 1, jh = wv & 1;
  if (ng >= ngrp) return;
  const int l = t & 63, clo = l & 15, kq = l >> 4;
  const int node = ng*16 + clo;
  const int nc = node < nN ? node : nN-1;

  float h[4][8];
  #pragma unroll
  for (int c=0; c<4; ++c){
    if (BF16IN){
      uint4 raw = *(const uint4*)(in16 + (size_t)nc*128 + c*32 + kq*8);
      h[c][0]=bflo(raw.x); h[c][1]=bfhi(raw.x);
      h[c][2]=bflo(raw.y); h[c][3]=bfhi(raw.y);
      h[c][4]=bflo(raw.z); h[c][5]=bfhi(raw.z);
      h[c][6]=bflo(raw.w); h[c][7]=bfhi(raw.w);
      #pragma unroll
      for (int u=0; u<8; ++u){
        int d = c*32 + kq*8 + u;
        h[c][u] = fmaf(h[c][u], sscsh[d], sscsh[128 + d]);
      }
    } else {
      const float* hrow = in32 + (size_t)nc*128;
      *(float4*)&h[c][0] = *(const float4*)(hrow + c*32 + kq*8);
      *(float4*)&h[c][4] = *(const float4*)(hrow + c*32 + kq*8 + 4);
    }
  }
  // fused LayerNorm stats
  float s = 0.f, sq = 0.f;
  #pragma unroll
  for (int c=0; c<4; ++c)
    #pragma unroll
    for (int u=0; u<8; ++u){ float v = h[c][u]; s += v; sq += v*v; }
  s  += __shfl_xor(s, 16, 64);  s  += __shfl_xor(s, 32, 64);
  sq += __shfl_xor(sq, 16, 64); sq += __shfl_xor(sq, 32, 64);
  float mean = s * (1.f/128.f);
  float var  = fmaxf(sq * (1.f/128.f) - mean*mean, 0.f);
  float rstd = rsqrtf(var + 1e-5f);

  f32x4 acc[4];
  #pragma unroll
  for (int j=0; j<4; ++j) acc[j] = (f32x4)0.f;

  for (int c=0; c<4; ++c){
    float lngv[8], lnbv[8];
    *(float4*)&lngv[0] = *(const float4*)(lng + c*32 + kq*8);
    *(float4*)&lngv[4] = *(const float4*)(lng + c*32 + kq*8 + 4);
    *(float4*)&lnbv[0] = *(const float4*)(lnb + c*32 + kq*8);
    *(float4*)&lnbv[4] = *(const float4*)(lnb + c*32 + kq*8 + 4);
    s8v a[5];
    build_frags(h[c], mean, rstd, lngv, lnbv, a);
    #pragma unroll
    for (int ks=0; ks<5; ++ks){
      const int kglob = c*5 + ks;
      #pragma unroll
      for (int j=0; j<4; ++j){
        s8v b = *(const s8v*)(wpre + ((size_t)((jh*4 + j)*20 + kglob)*64 + l)*8);
        acc[j] = __builtin_amdgcn_mfma_f32_16x16x32_bf16(a[ks], b, acc[j], 0, 0, 0);
      }
    }
  }
  // epilogue: C/D col = clo, row = kq*4+rr ; hs = (acc+bias)*disp[node], bf16
  float bv[4];
  #pragma unroll
  for (int j=0; j<4; ++j) bv[j] = bias[(jh*4 + j)*16 + clo];
  #pragma unroll
  for (int rr=0; rr<4; ++rr){
    int nw = ng*16 + kq*4 + rr;
    if (nw < nN){
      float dsc = disp[nw];
      #pragma unroll
      for (int j=0; j<4; ++j)
        hs[(size_t)nw*128 + (jh*4 + j)*16 + clo] = f2bf((acc[j][rr] + bv[j]) * dsc);
    }
  }
}

// ---------------- final FKAN: 8 waves x 2 chunks, 32 nodes/block; fused LN-512 + BN fold ----
__global__ __launch_bounds__(TPBO, 4) void fkan_out_k(
    const float* __restrict__ x, const u16* __restrict__ hl16,
    const float* __restrict__ statsL, const float* __restrict__ bng, const float* __restrict__ bnb,
    const float* __restrict__ lng, const float* __restrict__ lnb,
    const u16* __restrict__ wpre, const float* __restrict__ bias,
    float* __restrict__ out, int nN)
{
  __shared__ float sscshO[768];         // 3 layers x {sc[128], sh[128]}
  __shared__ float sstat[8][16][4];     // [wave][clo][{s0,q0,s1,q1}]
  __shared__ float sred[8][24][64];
  const int t = threadIdx.x;
  if (t < 384){
    int li = t >> 7, c = t & 127;
    float inv = 1.f/(float)nN;
    float m = statsL[li*256 + c]*inv;
    float var = fmaxf(statsL[li*256 + 128 + c]*inv - m*m, 0.f);
    float sc = bng[li*128 + c]*rsqrtf(var + 1e-5f);
    sscshO[li*256 + c] = sc;
    sscshO[li*256 + 128 + c] = bnb[li*128 + c] - m*sc;
  }
  __syncthreads();
  const int w = t >> 6, l = t & 63, clo = l & 15, kq = l >> 4;
  const int nb0 = blockIdx.x * 32;
  int nc0 = nb0 + clo;      nc0 = nc0 < nN ? nc0 : nN-1;
  int nc1 = nb0 + 16 + clo; nc1 = nc1 < nN ? nc1 : nN-1;

  // ---- load this wave's 2 chunks for both node groups (BN folded for hl part)
  float h0[2][8], h1[2][8];
  #pragma unroll
  for (int cc=0; cc<2; ++cc){
    const int c = w*2 + cc;
    const int d0 = c*32 + kq*8;
    if (d0 < 128){
      const float* s0 = x + (size_t)nc0*128 + d0;
      const float* s1 = x + (size_t)nc1*128 + d0;
      *(float4*)&h0[cc][0] = *(const float4*)(s0);  *(float4*)&h0[cc][4] = *(const float4*)(s0+4);
      *(float4*)&h1[cc][0] = *(const float4*)(s1);  *(float4*)&h1[cc][4] = *(const float4*)(s1+4);
    } else {
      int dd = d0 - 128, li = dd >> 7, cc2 = dd & 127;
      uint4 r0 = *(const uint4*)(hl16 + ((size_t)li*nN + nc0)*128 + cc2);
      uint4 r1 = *(const uint4*)(hl16 + ((size_t)li*nN + nc1)*128 + cc2);
      h0[cc][0]=bflo(r0.x); h0[cc][1]=bfhi(r0.x); h0[cc][2]=bflo(r0.y); h0[cc][3]=bfhi(r0.y);
      h0[cc][4]=bflo(r0.z); h0[cc][5]=bfhi(r0.z); h0[cc][6]=bflo(r0.w); h0[cc][7]=bfhi(r0.w);
      h1[cc][0]=bflo(r1.x); h1[cc][1]=bfhi(r1.x); h1[cc][2]=bflo(r1.y); h1[cc][3]=bfhi(r1.y);
      h1[cc][4]=bflo(r1.z); h1[cc][5]=bfhi(r1.z); h1[cc][6]=bflo(r1.w); h1[cc][7]=bfhi(r1.w);
      #pragma unroll
      for (int u=0; u<8; ++u){
        float sc = sscshO[li*256 + cc2 + u], sh = sscshO[li*256 + 128 + cc2 + u];
        h0[cc][u] = fmaf(h0[cc][u], sc, sh);
        h1[cc][u] = fmaf(h1[cc][u], sc, sh);
      }
    }
  }
  // ---- fused LN-512 stats: lane partial -> kq reduce -> cross-wave LDS reduce
  float s0=0.f, q0=0.f, s1=0.f, q1=0.f;
  #pragma unroll
  for (int cc=0; cc<2; ++cc)
    #pragma unroll
    for (int u=0; u<8; ++u){
      float a0v = h0[cc][u], a1v = h1[cc][u];
      s0 += a0v; q0 += a0v*a0v;
      s1 += a1v; q1 += a1v*a1v;
    }
  s0 += __shfl_xor(s0, 16, 64); s0 += __shfl_xor(s0, 32, 64);
  q0 += __shfl_xor(q0, 16, 64); q0 += __shfl_xor(q0, 32, 64);
  s1 += __shfl_xor(s1, 16, 64); s1 += __shfl_xor(s1, 32, 64);
  q1 += __shfl_xor(q1, 16, 64); q1 += __shfl_xor(q1, 32, 64);
  if (l < 16){
    sstat[w][clo][0] = s0; sstat[w][clo][1] = q0;
    sstat[w][clo][2] = s1; sstat[w][clo][3] = q1;
  }
  __syncthreads();
  float S0=0.f, Q0=0.f, S1=0.f, Q1=0.f;
  #pragma unroll
  for (int ww=0; ww<8; ++ww){
    S0 += sstat[ww][clo][0]; Q0 += sstat[ww][clo][1];
    S1 += sstat[ww][clo][2]; Q1 += sstat[ww][clo][3];
  }
  const float mean0 = S0 * (1.f/512.f);
  const float rstd0 = rsqrtf(fmaxf(Q0*(1.f/512.f) - mean0*mean0, 0.f) + 1e-5f);
  const float mean1 = S1 * (1.f/512.f);
  const float rstd1 = rsqrtf(fmaxf(Q1*(1.f/512.f) - mean1*mean1, 0.f) + 1e-5f);

  f32x4 acc[2][3];
  #pragma unroll
  for (int m=0; m<2; ++m)
    #pragma unroll
    for (int j=0; j<3; ++j) acc[m][j] = (f32x4)0.f;

  #pragma unroll
  for (int cc=0; cc<2; ++cc){
    const int c = w*2 + cc;
    const int d0 = c*32 + kq*8;
    float lngv[8], lnbv[8];
    *(float4*)&lngv[0] = *(const float4*)(lng + d0);
    *(float4*)&lngv[4] = *(const float4*)(lng + d0 + 4);
    *(float4*)&lnbv[0] = *(const float4*)(lnb + d0);
    *(float4*)&lnbv[4] = *(const float4*)(lnb + d0 + 4);
    s8v a0[5], a1[5];
    build_frags(h0[cc], mean0, rstd0, lngv, lnbv, a0);
    build_frags(h1[cc], mean1, rstd1, lngv, lnbv, a1);
    #pragma unroll
    for (int ks=0; ks<5; ++ks){
      const int kglob = c*5 + ks;
      #pragma unroll
      for (int j=0; j<3; ++j){
        s8v b = *(const s8v*)(wpre + ((size_t)(j*80 + kglob)*64 + l)*8);
        acc[0][j] = __builtin_amdgcn_mfma_f32_16x16x32_bf16(a0[ks], b, acc[0][j], 0, 0, 0);
        acc[1][j] = __builtin_amdgcn_mfma_f32_16x16x32_bf16(a1[ks], b, acc[1][j], 0, 0, 0);
      }
    }
  }
  #pragma unroll
  for (int m=0; m<2; ++m)
    #pragma unroll
    for (int j=0; j<3; ++j)
      #pragma unroll
      for (int rr=0; rr<4; ++rr)
        sred[w][m*12 + j*4 + rr][l] = acc[m][j][rr];
  __syncthreads();
  // parallel reduce + store: 24 slots x 64 lanes = 1536 items over 512 threads
  #pragma unroll
  for (int k=0; k<3; ++k){
    int q = t + k*TPBO;
    int slot = q >> 6, l2 = q & 63;
    float val = 0.f;
    #pragma unroll
    for (int ww=0; ww<8; ++ww) val += sred[ww][slot][l2];
    int m = slot >= 12 ? 1 : 0;
    int jrr = slot - m*12;
    int j = jrr >> 2, rr = jrr & 3;
    int nodeq = nb0 + m*16 + (l2 >> 4)*4 + rr;
    int col = j*16 + (l2 & 15);
    if (nodeq < nN && col < 40)
      out[(size_t)nodeq*40 + col] = val + bias[col];
  }
}

// ---------------- GCN aggregation: node-per-quarter-wave, depth-8 ----------------
__device__ __forceinline__ void acc_bf8(uint4 u, float* __restrict__ a){
  a[0] += bflo(u.x); a[1] += bfhi(u.x);
  a[2] += bflo(u.y); a[3] += bfhi(u.y);
  a[4] += bflo(u.z); a[5] += bfhi(u.z);
  a[6] += bflo(u.w); a[7] += bfhi(u.w);
}

__global__ __launch_bounds__(TPB) void gcn_k(const u16* __restrict__ hs, const int* __restrict__ rowptr,
                                             const int* __restrict__ csr, const float* __restrict__ disp,
                                             u16* __restrict__ hl, int nN){
  int g = blockIdx.x*TPB + threadIdx.x;
  int wv = g >> 6, lane = g & 63;
  const int li = lane & 15, qd = lane >> 4;
  int n = wv*4 + qd;                          // quarter-wave owns one node
  if (n >= nN) return;
  const uint4* H4 = (const uint4*)hs;         // 16 uint4 per row (128 bf16); lane li holds 16B slice
  int e0 = rowptr[n], e1 = rowptr[n+1];
  float a[8];
  #pragma unroll
  for (int j=0; j<8; ++j) a[j] = 0.f;
  for (int base = e0; base < e1; base += 8){  // 8 row-gathers in flight
    int r[8];
    #pragma unroll
    for (int k=0; k<8; ++k){
      int idx = base + k;
      int idc = idx < e1 ? idx : e1-1;        // safe address (loop implies e1>e0)
      int rv  = csr[idc];                     // uniform across the 16 lanes (L1 broadcast)
      r[k] = idx < e1 ? rv : nN;              // row nN = zero sentinel
    }
    #pragma unroll
    for (int k=0; k<8; ++k){
      uint4 u = H4[(size_t)r[k]*16 + li];
      acc_bf8(u, a);
    }
  }
  uint4 u = H4[(size_t)n*16 + li];            // self-loop (hs already has dis[n] factor)
  acc_bf8(u, a);
  float dn = disp[n];
  uint4 o;
  o.x = pack_bf2(a[0]*dn, a[1]*dn);
  o.y = pack_bf2(a[2]*dn, a[3]*dn);
  o.z = pack_bf2(a[4]*dn, a[5]*dn);
  o.w = pack_bf2(a[6]*dn, a[7]*dn);
  *(uint4*)(hl + (size_t)n*128 + li*8) = o;   // 256B contiguous per quarter
}

// ---------------- BatchNorm stats over bf16 hl (scale/shift computed in consumers) ----------
__global__ __launch_bounds__(TPB) void bn_stat_k(const u16* __restrict__ hl, float* __restrict__ stats, int nN){
  int cp   = threadIdx.x & 63;     // column pair (2 bf16 per dword)
  int strm = threadIdx.x >> 6;     // 4 row streams
  const unsigned* H = (const unsigned*)hl;
  float s0=0.f, s1=0.f, q0=0.f, q1=0.f;
  for (int r = blockIdx.x*4 + strm; r < nN; r += gridDim.x*4){
    unsigned u = H[(size_t)r*64 + cp];
    float lo = bflo(u), hi = bfhi(u);
    s0 += lo; q0 += lo*lo; s1 += hi; q1 += hi*hi;
  }
  __shared__ float ls[4][64][4];
  ls[strm][cp][0] = s0; ls[strm][cp][1] = q0; ls[strm][cp][2] = s1; ls[strm][cp][3] = q1;
  __syncthreads();
  if (strm == 0){
    float S0 = ls[0][cp][0]+ls[1][cp][0]+ls[2][cp][0]+ls[3][cp][0];
    float Q0 = ls[0][cp][1]+ls[1][cp][1]+ls[2][cp][1]+ls[3][cp][1];
    float S1 = ls[0][cp][2]+ls[1][cp][2]+ls[2][cp][2]+ls[3][cp][2];
    float Q1 = ls[0][cp][3]+ls[1][cp][3]+ls[2][cp][3]+ls[3][cp][3];
    atomicAdd(&stats[cp*2],       S0);
    atomicAdd(&stats[cp*2+1],     S1);
    atomicAdd(&stats[128+cp*2],   Q0);
    atomicAdd(&stats[128+cp*2+1], Q1);
  }
}

extern "C" void kernel_launch(void* const* d_in, const int* in_sizes, int n_in,
                              void* d_out, int out_size, void* d_ws, size_t ws_size,
                              hipStream_t stream)
{
  const float* x        = (const float*)d_in[0];
  const int*   ei       = (const int*)d_in[1];
  const float* ln_g     = (const float*)d_in[2];
  const float* ln_b     = (const float*)d_in[3];
  const float* sw       = (const float*)d_in[4];
  const float* bw       = (const float*)d_in[5];
  const float* bb       = (const float*)d_in[6];
  // d_in[7] gcn_bias: canceled exactly by BatchNorm mean subtraction. Skipped.
  const float* bn_g     = (const float*)d_in[8];
  const float* bn_b     = (const float*)d_in[9];
  const float* ln_g_out = (const float*)d_in[10];
  const float* ln_b_out = (const float*)d_in[11];
  const float* sw_out   = (const float*)d_in[12];
  const float* bw_out   = (const float*)d_in[13];
  const float* bb_out   = (const float*)d_in[14];
  float* out = (float*)d_out;

  const int nN = in_sizes[0] / 128;    // 50000
  const int E  = in_sizes[1] / 2;      // 800000

  char* ws = (char*)d_ws;
  size_t off = 0;
  auto alloc = [&](size_t bytes)->char*{
    char* p = ws + off; off = (off + bytes + 255) & ~size_t(255); return p;
  };
  u16*   hl16  = (u16*)alloc((size_t)3*nN*128*2);   // per-layer raw GCN aggregate, bf16
  u16*   hs    = (u16*)alloc((size_t)(nN+1)*128*2); // pre-scaled bf16 FKAN output + zero sentinel row
  float* disp  = (float*)alloc((size_t)nN*4);
  u16*   wpreL = (u16*)alloc((size_t)3*8*20*512*2); // per-layer staged weights
  u16*   wpreO = (u16*)alloc((size_t)3*80*512*2);
  // ---- contiguous zero region: statsL + cnt + cursor (one memset)
  size_t zbeg = off;
  float* statsL = (float*)alloc(3*256*4);           // per-layer raw BN sums
  int* cnt     = (int*)alloc((size_t)nN*4);
  int* cursor  = (int*)alloc((size_t)nN*4);
  size_t zend = off;
  int* rowptr  = (int*)alloc((size_t)(nN+1)*4);
  int* bsum    = (int*)alloc(256*4);
  int* csr     = (int*)alloc((size_t)E*4);
  (void)ws_size; (void)n_in; (void)out_size;

  const int* srcE = ei;
  const int* dstE = ei + E;

  hipMemsetAsync(ws + zbeg, 0, zend - zbeg, stream);
  hipMemsetAsync(hs + (size_t)nN*128, 0, 256, stream);   // zero sentinel row

  // stage all weights up-front (overlaps with CSR build)
  for (int i=0; i<3; ++i)
    prep_wpre_k<<<(8*20*512 + TPB-1)/TPB, TPB, 0, stream>>>(
        sw + (size_t)i*128*512, bw + (size_t)i*128*128, wpreL + (size_t)i*8*20*512, 128, 20, 8, 128);
  prep_wpre_k<<<(3*80*512 + TPB-1)/TPB, TPB, 0, stream>>>(
      sw_out, bw_out, wpreO, 512, 80, 3, 40);

  const int nbE = (E + TPB-1)/TPB;
  const int nbN = (nN + TPB-1)/TPB;
  count_k<<<nbE, TPB, 0, stream>>>(dstE, cnt, E);
  scan1_k<<<nbN, TPB, 0, stream>>>(cnt, rowptr, bsum, disp, nN);
  scan3_k<<<nbN, TPB, 0, stream>>>(rowptr, bsum, nN, E, nbN);
  fill_k<<<nbE, TPB, 0, stream>>>(srcE, dstE, rowptr, cursor, csr, E);

  const int nbG = (((nN + 3)/4)*64 + TPB-1)/TPB;        // gcn: node per quarter-wave
  const int nbL = (((nN + 15)/16)*2 + 3)/4;             // fkan layer: 2 j-half waves per 16 nodes
  const int nbO = (nN + 31)/32;                         // fkan out: 32 nodes/block, 8-wave K-split

  for (int i=0; i<3; ++i){
    if (i == 0){
      fkan_layer_k<false><<<nbL, TPB, 0, stream>>>(
          x, (const u16*)nullptr, (const float*)nullptr, (const float*)nullptr, (const float*)nullptr,
          ln_g, ln_b, wpreL, bb, disp, hs, nN);
    } else {
      fkan_layer_k<true><<<nbL, TPB, 0, stream>>>(
          (const float*)nullptr, hl16 + (size_t)(i-1)*nN*128,
          statsL + (size_t)(i-1)*256, bn_g + (size_t)(i-1)*128, bn_b + (size_t)(i-1)*128,
          ln_g + (size_t)i*128, ln_b + (size_t)i*128,
          wpreL + (size_t)i*8*20*512, bb + (size_t)i*128, disp, hs, nN);
    }
    gcn_k<<<nbG, TPB, 0, stream>>>(hs, rowptr, csr, disp, hl16 + (size_t)i*nN*128, nN);
    bn_stat_k<<<256, TPB, 0, stream>>>(hl16 + (size_t)i*nN*128, statsL + (size_t)i*256, nN);
  }

  // final FKAN on concat [x | BN(hl)]  (512 -> 40), LN + BN-fin fused in-kernel
  fkan_out_k<<<nbO, TPBO, 0, stream>>>(
      x, hl16, statsL, bn_g, bn_b, ln_g_out, ln_b_out, wpreO, bb_out, out, nN);
}